// Round 17
// baseline (57.837 us; speedup 1.0000x reference)
//
#include <hip/hip_runtime.h>
#include <hip/hip_bf16.h>

#define BSZ   4096
#define NCON  8192
#define DFEAT 256
#define C2    20.60992914f    // (1/0.07)*log2(e): logits-minus-max in log2 units
#define LN2   0.6931471806f

#define BJM 32                // jm rows per tile (covers cols jm AND jm+4096)
#define BI 128                // i-rows per block (4 waves x 32)
#define NJT 8                 // jm-tiles per block
#define JSTRIP_M (NJT * BJM)  // 256 jm per block (512 logit-cols)

typedef __attribute__((ext_vector_type(8))) short short8;
typedef __attribute__((ext_vector_type(4))) float f32x4;

__device__ __forceinline__ unsigned short f2bf(float f) {
    __hip_bfloat16 h = __float2bfloat16(f);
    return *reinterpret_cast<unsigned short*>(&h);
}

__device__ __forceinline__ void gload_lds16(const void* g, void* l) {
    __builtin_amdgcn_global_load_lds(
        (const __attribute__((address_space(1))) unsigned int*)g,
        (__attribute__((address_space(3))) unsigned int*)l,
        16, 0, 0);
}

// Volatile asm load: cannot be rematerialized/sunk — keeps Y register-resident.
__device__ __forceinline__ void gload_reg16(const void* p, short8& dst) {
    unsigned long long a = (unsigned long long)p;
    asm volatile("global_load_dwordx4 %0, %1, off"
                 : "=v"(dst) : "v"(a));
}

// ws layout: [0, 4MB) contrast bf16 [NCON][DFEAT]; then f32 S[4096], A[4096], B[4096]

__global__ __launch_bounds__(256) void k_prep(const float* __restrict__ feat,
                                              unsigned short* __restrict__ con,
                                              float* __restrict__ acc) {
    int idx = blockIdx.x * 256 + threadIdx.x;
    int e = idx * 4;
    int j = e >> 8;
    int k = e & 255;
    int src = (j < BSZ) ? ((j * 2) * DFEAT + k)
                        : (((j - BSZ) * 2 + 1) * DFEAT + k);
    float4 f = *(const float4*)(feat + src);
    ushort4 o;
    o.x = f2bf(f.x); o.y = f2bf(f.y); o.z = f2bf(f.z); o.w = f2bf(f.w);
    *(ushort4*)(con + e) = o;
    if (idx < 3 * BSZ) acc[idx] = 0.0f;
}

// lX panel per view (16 KB): 4 sub-panels [k2][row 0..31][64 cols], 128B row
// stride — swizzle pattern verified 0 bank conflicts (R13 layout).
__global__ __launch_bounds__(256) void k_main(const __hip_bfloat16* __restrict__ conp,
                                              const float* __restrict__ va,
                                              const int* __restrict__ dia,
                                              const int* __restrict__ thr_ptr,
                                              float* __restrict__ Srow,
                                              float* __restrict__ Arow,
                                              float* __restrict__ Brow) {
    __shared__ short lX[2][2][BJM * DFEAT];      // [dbuf][view][8192] = 64 KB
    __shared__ float4 s_meta[JSTRIP_M];          // {vjx, vjy, bitcast(dj), 0}: 4 KB

    const int tid  = threadIdx.x;
    const int lane = tid & 63;
    const int wv   = tid >> 6;
    const int l15  = lane & 15;
    const int hi   = lane >> 4;
    const int jmbase = blockIdx.x * JSTRIP_M;       // [0, 4096)
    const int ibase  = blockIdx.y * BI + wv * 32;   // this wave's 32 anchor rows
    const short* cs = (const short*)conp;

    // Per-thread staging pointers: swizzled source is LINEAR in jt (stride 8192
    // elems = 32 rows). Compute once, increment per tile.
    const short* pg[2][4];
    #pragma unroll
    for (int v = 0; v < 2; ++v)
        #pragma unroll
        for (int q = 0; q < 4; ++q) {
            int e   = q * 2048 + tid * 8;      // element in [0, 8192)
            int col = e & 63;
            int row = (e >> 6) & 31;
            int k2  = e >> 11;                 // 64-col sub-panel (0..3)
            int scol = col ^ ((row & 7) << 3); // involution pre-swizzle
            pg[v][q] = cs + (size_t)(jmbase + row + v * BSZ) * DFEAT + k2 * 64 + scol;
        }

    auto stageX = [&](int buf) {
        #pragma unroll
        for (int v = 0; v < 2; ++v)
            #pragma unroll
            for (int q = 0; q < 4; ++q) {
                gload_lds16(pg[v][q], &lX[buf][v][q * 2048 + tid * 8]);
                pg[v][q] += BJM * DFEAT;       // next jm-tile (8192 elems)
            }
    };

    stageX(0);

    // ---- Y panel to registers (volatile asm; 64 regs, resident) ----
    const short* yrow0 = cs + (size_t)(ibase + l15) * DFEAT + hi * 8;
    short8 y[2][8];
    #pragma unroll
    for (int n = 0; n < 2; ++n)
        #pragma unroll
        for (int s = 0; s < 8; ++s)
            gload_reg16(yrow0 + (size_t)n * 16 * DFEAT + s * 32, y[n][s]);

    // ---- strip metadata, packed (256 jm entries) ----
    {
        int jm = jmbase + tid;
        s_meta[tid] = make_float4(va[2 * jm], va[2 * jm + 1],
                                  __int_as_float(dia[jm]), 0.0f);
    }

    int raw = *thr_ptr;
    float t_ = (raw > 0 && raw < 100000) ? (float)raw : __int_as_float(raw);
    float thres2 = t_ * t_;

    float vix[2], viy[2]; int di[2], ig[2];
    #pragma unroll
    for (int n = 0; n < 2; ++n) {
        ig[n] = ibase + n * 16 + l15;
        vix[n] = va[2 * ig[n]]; viy[n] = va[2 * ig[n] + 1]; di[n] = dia[ig[n]];
    }

    float sp[2] = {0.f, 0.f};
    float ap[2] = {0.f, 0.f};   // log2 units; Σ mk·(l0+l1)
    float bp[2] = {0.f, 0.f};   // Σ mk  (B = 2·bp − 1, applied in k_final)

    __syncthreads();                                   // drains staging + Y loads
    asm volatile("s_waitcnt vmcnt(0)" ::: "memory");
    __builtin_amdgcn_sched_barrier(0);

    for (int jt = 0; jt < NJT; ++jt) {
        const int cur = jt & 1;
        if (jt < NJT - 1) stageX(cur ^ 1);             // stream next tile under compute

        f32x4 acc[2][2][2];   // [view][m = jm-frag][n = i-frag]
        #pragma unroll
        for (int v = 0; v < 2; ++v)
            #pragma unroll
            for (int m = 0; m < 2; ++m)
                #pragma unroll
                for (int n = 0; n < 2; ++n)
                    acc[v][m][n] = (f32x4){0.f, 0.f, 0.f, 0.f};

        __builtin_amdgcn_s_setprio(1);
        #pragma unroll
        for (int s = 0; s < 8; ++s) {
            const int base = (s >> 1) * 4096;          // sub-panel byte base (32x128B)
            const int colb = (s & 1) * 64 + hi * 16;   // byte col in sub-panel
            short8 xf[2][2];
            #pragma unroll
            for (int v = 0; v < 2; ++v)
                #pragma unroll
                for (int m = 0; m < 2; ++m) {
                    int row = m * 16 + l15;
                    xf[v][m] = *(const short8*)((const char*)&lX[cur][v][0]
                                 + base + row * 128 + (colb ^ ((row & 7) << 4)));
                }
            #pragma unroll
            for (int v = 0; v < 2; ++v)
                #pragma unroll
                for (int m = 0; m < 2; ++m)
                    #pragma unroll
                    for (int n = 0; n < 2; ++n)
                        acc[v][m][n] = __builtin_amdgcn_mfma_f32_16x16x32_bf16(
                            xf[v][m], y[n][s], acc[v][m][n], 0, 0, 0);
        }
        __builtin_amdgcn_s_setprio(0);

        // epilogue: trimmed (mask once; diag ⊂ same_dia; B end-corrected)
        const int jt0 = jt * BJM;
        #pragma unroll
        for (int m = 0; m < 2; ++m)
            #pragma unroll
            for (int r = 0; r < 4; ++r) {
                const int jl  = jt0 + m * 16 + hi * 4 + r;
                const int jmg = jmbase + jl;
                float4 md = s_meta[jl];
                int dj = __float_as_int(md.z);
                #pragma unroll
                for (int n = 0; n < 2; ++n) {
                    float l0 = __builtin_fmaf(acc[0][m][n][r], C2, -C2);
                    float l1 = __builtin_fmaf(acc[1][m][n][r], C2, -C2);
                    float dx = vix[n] - md.x, dy = viy[n] - md.y;
                    bool diag = (ig[n] == jmg);
                    bool mk = (di[n] == dj) | (dx * dx + dy * dy < thres2);
                    float e0 = diag ? 0.0f : exp2f(l0);   // exact diag exclusion (S)
                    float e1 = exp2f(l1);
                    sp[n] += e0 + e1;
                    float mm = mk ? 1.0f : 0.0f;
                    ap[n] = __builtin_fmaf(mm, l0 + l1, ap[n]);
                    bp[n] += mm;
                }
            }
        __syncthreads();   // next iter overwrites the buffer we just computed from
    }

    // ---- reduce across hi-groups, one atomic set per wave ----
    #pragma unroll
    for (int n = 0; n < 2; ++n) {
        float s = sp[n], a = ap[n], b = bp[n];
        s += __shfl_xor(s, 16, 64);  a += __shfl_xor(a, 16, 64);  b += __shfl_xor(b, 16, 64);
        s += __shfl_xor(s, 32, 64);  a += __shfl_xor(a, 32, 64);  b += __shfl_xor(b, 32, 64);
        if (hi == 0) {
            atomicAdd(&Srow[ig[n]], s);
            atomicAdd(&Arow[ig[n]], a * LN2);   // log2 -> natural units
            atomicAdd(&Brow[ig[n]], b);
        }
    }
}

__global__ __launch_bounds__(256) void k_final(const float* __restrict__ S,
                                               const float* __restrict__ A,
                                               const float* __restrict__ B,
                                               float* __restrict__ out) {
    __shared__ float red[256];
    float sum = 0.f;
    for (int i = threadIdx.x; i < BSZ; i += 256) {
        float b = 2.0f * B[i] - 1.0f;        // B = 2·Σmk − diag
        float v = (A[i] - b * logf(S[i] + 1e-10f)) / (b + 1e-10f);
        sum += -v;
    }
    red[threadIdx.x] = sum;
    __syncthreads();
    for (int s = 128; s > 0; s >>= 1) {
        if (threadIdx.x < s) red[threadIdx.x] += red[threadIdx.x + s];
        __syncthreads();
    }
    if (threadIdx.x == 0) out[0] = red[0] / (float)BSZ;
}

extern "C" void kernel_launch(void* const* d_in, const int* in_sizes, int n_in,
                              void* d_out, int out_size, void* d_ws, size_t ws_size,
                              hipStream_t stream) {
    const float* feat = (const float*)d_in[0];
    const float* va   = (const float*)d_in[1];
    const int*   dia  = (const int*)d_in[2];
    const int*   thr  = (const int*)d_in[3];

    unsigned short* con = (unsigned short*)d_ws;
    float* acc = (float*)((char*)d_ws + (size_t)NCON * DFEAT * 2);
    float* out = (float*)d_out;

    k_prep<<<(NCON * DFEAT / 4 + 255) / 256, 256, 0, stream>>>(feat, con, acc);

    dim3 grid(BSZ / JSTRIP_M, BSZ / BI);   // (16, 32) = 512 blocks
    k_main<<<grid, 256, 0, stream>>>((const __hip_bfloat16*)con, va, dia, thr,
                                     acc, acc + BSZ, acc + 2 * BSZ);

    k_final<<<1, 256, 0, stream>>>(acc, acc + BSZ, acc + 2 * BSZ, out);
}

// Round 18
// 47.006 us; speedup vs baseline: 1.2304x; 1.2304x over previous
//
#include <hip/hip_runtime.h>
#include <hip/hip_bf16.h>

#define BSZ   4096
#define NCON  8192
#define DFEAT 256
#define C2    20.60992914f    // (1/0.07)*log2(e): logits-minus-max in log2 units
#define LN2   0.6931471806f

#define BJM 32                // jm per tile (each tile covers cols jm AND jm+4096)
#define BI 128                // i-rows per block (4 waves x 32)
#define NJT 8                 // jm-tiles per block
#define JSTRIP_M (NJT * BJM)  // 256 jm per block (512 logit-cols)

typedef __attribute__((ext_vector_type(8))) short short8;
typedef __attribute__((ext_vector_type(4))) float f32x4;

__device__ __forceinline__ unsigned short f2bf(float f) {
    __hip_bfloat16 h = __float2bfloat16(f);
    return *reinterpret_cast<unsigned short*>(&h);
}

__device__ __forceinline__ void gload_lds16(const void* g, void* l) {
    __builtin_amdgcn_global_load_lds(
        (const __attribute__((address_space(1))) unsigned int*)g,
        (__attribute__((address_space(3))) unsigned int*)l,
        16, 0, 0);
}

// Volatile asm load: cannot be rematerialized/sunk — keeps Y register-resident.
__device__ __forceinline__ void gload_reg16(const void* p, short8& dst) {
    unsigned long long a = (unsigned long long)p;
    asm volatile("global_load_dwordx4 %0, %1, off"
                 : "=v"(dst) : "v"(a));
}

// ws layout: [0, 4MB) contrast bf16 [NCON][DFEAT]; then f32 S[4096], A[4096], B[4096]

__global__ __launch_bounds__(256) void k_prep(const float* __restrict__ feat,
                                              unsigned short* __restrict__ con,
                                              float* __restrict__ acc) {
    int idx = blockIdx.x * 256 + threadIdx.x;
    int e = idx * 4;
    int j = e >> 8;
    int k = e & 255;
    int src = (j < BSZ) ? ((j * 2) * DFEAT + k)
                        : (((j - BSZ) * 2 + 1) * DFEAT + k);
    float4 f = *(const float4*)(feat + src);
    ushort4 o;
    o.x = f2bf(f.x); o.y = f2bf(f.y); o.z = f2bf(f.z); o.w = f2bf(f.w);
    *(ushort4*)(con + e) = o;
    if (idx < 3 * BSZ) acc[idx] = 0.0f;
}

// lX panel per view (16 KB): 4 sub-panels [k2][row 0..31][64 cols], 128B row
// stride — swizzle pattern verified 0 bank conflicts (R13 layout, verbatim).
__global__ __launch_bounds__(256, 2) void k_main(const __hip_bfloat16* __restrict__ conp,
                                                 const float* __restrict__ va,
                                                 const int* __restrict__ dia,
                                                 const int* __restrict__ thr_ptr,
                                                 float* __restrict__ Srow,
                                                 float* __restrict__ Arow,
                                                 float* __restrict__ Brow) {
    __shared__ short lX[2][2][BJM * DFEAT];      // [dbuf][view][8192] = 64 KB
    __shared__ float s_vjx[JSTRIP_M], s_vjy[JSTRIP_M];
    __shared__ int   s_dj[JSTRIP_M];

    const int tid  = threadIdx.x;
    const int lane = tid & 63;
    const int wv   = tid >> 6;
    const int l15  = lane & 15;
    const int hi   = lane >> 4;
    const int jmbase = blockIdx.x * JSTRIP_M;       // [0, 4096)
    const int ibase  = blockIdx.y * BI + wv * 32;   // this wave's 32 anchor rows
    const short* cs = (const short*)conp;

    auto stageX = [&](int buf, int jt) {
        #pragma unroll
        for (int v = 0; v < 2; ++v) {
            #pragma unroll
            for (int q = 0; q < 4; ++q) {
                int e   = q * 2048 + tid * 8;      // element in [0, 8192)
                int col = e & 63;
                int row = (e >> 6) & 31;
                int k2  = e >> 11;                 // 64-col sub-panel (0..3)
                int scol = col ^ ((row & 7) << 3); // involution pre-swizzle
                gload_lds16(cs + (size_t)(jmbase + jt * BJM + row + v * BSZ) * DFEAT
                               + k2 * 64 + scol,
                            &lX[buf][v][e]);
            }
        }
    };

    stageX(0, 0);

    // ---- Y panel to registers (volatile asm; 64 regs, resident) ----
    const short* yrow0 = cs + (size_t)(ibase + l15) * DFEAT + hi * 8;
    short8 y[2][8];
    #pragma unroll
    for (int n = 0; n < 2; ++n)
        #pragma unroll
        for (int s = 0; s < 8; ++s)
            gload_reg16(yrow0 + (size_t)n * 16 * DFEAT + s * 32, y[n][s]);

    // ---- strip metadata (256 jm entries) ----
    if (tid < JSTRIP_M) {
        int jm = jmbase + tid;
        s_vjx[tid] = va[2 * jm]; s_vjy[tid] = va[2 * jm + 1]; s_dj[tid] = dia[jm];
    }

    int raw = *thr_ptr;
    float t_ = (raw > 0 && raw < 100000) ? (float)raw : __int_as_float(raw);
    float thres2 = t_ * t_;

    float vix[2], viy[2]; int di[2], ig[2];
    #pragma unroll
    for (int n = 0; n < 2; ++n) {
        ig[n] = ibase + n * 16 + l15;
        vix[n] = va[2 * ig[n]]; viy[n] = va[2 * ig[n] + 1]; di[n] = dia[ig[n]];
    }

    float sp[2] = {0.f, 0.f};
    float ap[2] = {0.f, 0.f};   // log2 units; Σ mk·(l0+l1)
    float bp[2] = {0.f, 0.f};   // Σ mk  (B = 2·bp − 1, applied in k_final)

    __syncthreads();                                   // drains staging + Y loads
    asm volatile("s_waitcnt vmcnt(0)" ::: "memory");
    __builtin_amdgcn_sched_barrier(0);

    for (int jt = 0; jt < NJT; ++jt) {
        const int cur = jt & 1;
        if (jt < NJT - 1) stageX(cur ^ 1, jt + 1);     // stream next tile under compute

        f32x4 acc[2][2][2];   // [view][m = jm-frag][n = i-frag]
        #pragma unroll
        for (int v = 0; v < 2; ++v)
            #pragma unroll
            for (int m = 0; m < 2; ++m)
                #pragma unroll
                for (int n = 0; n < 2; ++n)
                    acc[v][m][n] = (f32x4){0.f, 0.f, 0.f, 0.f};

        __builtin_amdgcn_s_setprio(1);
        #pragma unroll
        for (int s = 0; s < 8; ++s) {
            const int base = (s >> 1) * 4096;          // sub-panel byte base (32x128B)
            const int colb = (s & 1) * 64 + hi * 16;   // byte col in sub-panel
            short8 xf[2][2];
            #pragma unroll
            for (int v = 0; v < 2; ++v)
                #pragma unroll
                for (int m = 0; m < 2; ++m) {
                    int row = m * 16 + l15;
                    xf[v][m] = *(const short8*)((const char*)&lX[cur][v][0]
                                 + base + row * 128 + (colb ^ ((row & 7) << 4)));
                }
            #pragma unroll
            for (int v = 0; v < 2; ++v)
                #pragma unroll
                for (int m = 0; m < 2; ++m)
                    #pragma unroll
                    for (int n = 0; n < 2; ++n)
                        acc[v][m][n] = __builtin_amdgcn_mfma_f32_16x16x32_bf16(
                            xf[v][m], y[n][s], acc[v][m][n], 0, 0, 0);
        }
        __builtin_amdgcn_s_setprio(0);

        // epilogue: trimmed (mask once; diag ⊂ same_dia; B end-corrected)
        const int jt0 = jt * BJM;
        #pragma unroll
        for (int m = 0; m < 2; ++m)
            #pragma unroll
            for (int r = 0; r < 4; ++r) {
                const int jl  = jt0 + m * 16 + hi * 4 + r;   // local jm in strip
                const int jmg = jmbase + jl;                 // global jm [0,4096)
                float vjx = s_vjx[jl], vjy = s_vjy[jl];
                int dj = s_dj[jl];
                #pragma unroll
                for (int n = 0; n < 2; ++n) {
                    float l0 = __builtin_fmaf(acc[0][m][n][r], C2, -C2);
                    float l1 = __builtin_fmaf(acc[1][m][n][r], C2, -C2);
                    float dx = vix[n] - vjx, dy = viy[n] - vjy;
                    bool diag = (ig[n] == jmg);
                    bool mk = (di[n] == dj) | (dx * dx + dy * dy < thres2);
                    float e0 = diag ? 0.0f : exp2f(l0);      // exact diag exclusion (S)
                    float e1 = exp2f(l1);
                    sp[n] += e0 + e1;
                    float mm = mk ? 1.0f : 0.0f;
                    ap[n] = __builtin_fmaf(mm, l0 + l1, ap[n]);
                    bp[n] += mm;
                }
            }
        __syncthreads();   // next iter overwrites the buffer we just computed from
    }

    // ---- reduce across hi-groups, one atomic set per wave ----
    #pragma unroll
    for (int n = 0; n < 2; ++n) {
        float s = sp[n], a = ap[n], b = bp[n];
        s += __shfl_xor(s, 16, 64);  a += __shfl_xor(a, 16, 64);  b += __shfl_xor(b, 16, 64);
        s += __shfl_xor(s, 32, 64);  a += __shfl_xor(a, 32, 64);  b += __shfl_xor(b, 32, 64);
        if (hi == 0) {
            atomicAdd(&Srow[ig[n]], s);
            atomicAdd(&Arow[ig[n]], a * LN2);   // log2 -> natural units
            atomicAdd(&Brow[ig[n]], b);
        }
    }
}

__global__ __launch_bounds__(256) void k_final(const float* __restrict__ S,
                                               const float* __restrict__ A,
                                               const float* __restrict__ B,
                                               float* __restrict__ out) {
    __shared__ float red[256];
    float sum = 0.f;
    for (int i = threadIdx.x; i < BSZ; i += 256) {
        float b = 2.0f * B[i] - 1.0f;        // B = 2·Σmk − diag
        float v = (A[i] - b * logf(S[i] + 1e-10f)) / (b + 1e-10f);
        sum += -v;
    }
    red[threadIdx.x] = sum;
    __syncthreads();
    for (int s = 128; s > 0; s >>= 1) {
        if (threadIdx.x < s) red[threadIdx.x] += red[threadIdx.x + s];
        __syncthreads();
    }
    if (threadIdx.x == 0) out[0] = red[0] / (float)BSZ;
}

extern "C" void kernel_launch(void* const* d_in, const int* in_sizes, int n_in,
                              void* d_out, int out_size, void* d_ws, size_t ws_size,
                              hipStream_t stream) {
    const float* feat = (const float*)d_in[0];
    const float* va   = (const float*)d_in[1];
    const int*   dia  = (const int*)d_in[2];
    const int*   thr  = (const int*)d_in[3];

    unsigned short* con = (unsigned short*)d_ws;
    float* acc = (float*)((char*)d_ws + (size_t)NCON * DFEAT * 2);
    float* out = (float*)d_out;

    k_prep<<<(NCON * DFEAT / 4 + 255) / 256, 256, 0, stream>>>(feat, con, acc);

    dim3 grid(BSZ / JSTRIP_M, BSZ / BI);   // (16, 32) = 512 blocks
    k_main<<<grid, 256, 0, stream>>>((const __hip_bfloat16*)con, va, dia, thr,
                                     acc, acc + BSZ, acc + 2 * BSZ);

    k_final<<<1, 256, 0, stream>>>(acc, acc + BSZ, acc + 2 * BSZ, out);
}